// Round 8
// baseline (423.758 us; speedup 1.0000x reference)
//
#include <hip/hip_runtime.h>
#include <hip/hip_bf16.h>
#include <math.h>

#define NT 2048
#define EMBD 512
#define NH 8
#define QKV_LD 1536

typedef unsigned short u16;
typedef __attribute__((ext_vector_type(8))) short short8;
typedef __attribute__((ext_vector_type(4))) float v4f;

static __device__ __forceinline__ float bf2f(unsigned int u) {
    union { unsigned int i; float f; } c; c.i = u << 16; return c.f;
}
static __device__ __forceinline__ unsigned int f2bf(float x) {   // RNE
    union { float f; unsigned int u; } c; c.f = x;
    return (c.u + 0x7fffu + ((c.u >> 16) & 1u)) >> 16;
}

// ------- split x into bf16 hi/lo --------------------------------------------
__global__ __launch_bounds__(256) void split_x(const float* __restrict__ x,
    u16* __restrict__ xh, u16* __restrict__ xl)
{
    int i = (blockIdx.x * 256 + threadIdx.x) << 2;
    float4 v = *(const float4*)(x + i);
    float f[4] = {v.x, v.y, v.z, v.w};
    unsigned int hi[4], lo[4];
#pragma unroll
    for (int j = 0; j < 4; ++j) {
        hi[j] = f2bf(f[j]);
        lo[j] = f2bf(f[j] - bf2f(hi[j]));
    }
    uint2 wh; wh.x = hi[0] | (hi[1] << 16); wh.y = hi[2] | (hi[3] << 16);
    uint2 wl; wl.x = lo[0] | (lo[1] << 16); wl.y = lo[2] | (lo[3] << 16);
    *(uint2*)(xh + i) = wh;
    *(uint2*)(xl + i) = wl;
}

// ------- split+transpose W[K][N] -> Wt[n][k] bf16 hi/lo (row stride ld) -----
__global__ __launch_bounds__(256) void split_wt(const float* __restrict__ W,
    u16* __restrict__ wth, u16* __restrict__ wtl, int ld)
{
    __shared__ float tile[64][65];
    const int n0 = blockIdx.x << 6, k0 = blockIdx.y << 6;
    const int t = threadIdx.x;
    const int r = t >> 2, c4 = (t & 3) << 4;
#pragma unroll
    for (int j = 0; j < 4; ++j)
        *(float4*)&tile[r][c4 + (j << 2)] =
            *(const float4*)(W + (size_t)(k0 + r) * ld + n0 + c4 + (j << 2));
    __syncthreads();
    const int n_l = t >> 2;
    u16 th[16], tl[16];
#pragma unroll
    for (int j = 0; j < 16; ++j) {
        float f = tile[c4 + j][n_l];
        unsigned int h = f2bf(f);
        th[j] = (u16)h;
        tl[j] = (u16)f2bf(f - bf2f(h));
    }
    u16* dh = wth + (size_t)(n0 + n_l) * EMBD + k0 + c4;
    u16* dl = wtl + (size_t)(n0 + n_l) * EMBD + k0 + c4;
    *(uint4*)dh       = *(uint4*)&th[0];
    *(uint4*)(dh + 8) = *(uint4*)&th[8];
    *(uint4*)dl       = *(uint4*)&tl[0];
    *(uint4*)(dl + 8) = *(uint4*)&tl[8];
}

// ------- qkv = x @ Wqkv + b via split-precision bf16 MFMA -------------------
__global__ __launch_bounds__(256) void gemm_qkv_mfma(const u16* __restrict__ xh,
    const u16* __restrict__ xl, const u16* __restrict__ wth,
    const u16* __restrict__ wtl, const float* __restrict__ bias,
    u16* __restrict__ qkvb)
{
    const int n0 = blockIdx.x << 6, m0 = blockIdx.y << 6;
    const int w = threadIdx.x >> 6, lane = threadIdx.x & 63;
    const int wm = w >> 1, wn = w & 1;
    const int fr = lane & 15, kd = (lane >> 4) << 3;

    const u16* ah0 = xh + (size_t)(m0 + wm * 32 + fr) * EMBD + kd;
    const u16* al0 = xl + (size_t)(m0 + wm * 32 + fr) * EMBD + kd;
    const u16* bh0 = wth + (size_t)(n0 + wn * 32 + fr) * EMBD + kd;
    const u16* bl0 = wtl + (size_t)(n0 + wn * 32 + fr) * EMBD + kd;

    v4f acc[2][2] = {};
    for (int kc = 0; kc < EMBD; kc += 32) {
        short8 a_h[2], a_l[2], b_h[2], b_l[2];
#pragma unroll
        for (int im = 0; im < 2; ++im) {
            a_h[im] = *(const short8*)(ah0 + (size_t)im * 16 * EMBD + kc);
            a_l[im] = *(const short8*)(al0 + (size_t)im * 16 * EMBD + kc);
        }
#pragma unroll
        for (int in = 0; in < 2; ++in) {
            b_h[in] = *(const short8*)(bh0 + (size_t)in * 16 * EMBD + kc);
            b_l[in] = *(const short8*)(bl0 + (size_t)in * 16 * EMBD + kc);
        }
#pragma unroll
        for (int im = 0; im < 2; ++im)
#pragma unroll
            for (int in = 0; in < 2; ++in) {
                acc[im][in] = __builtin_amdgcn_mfma_f32_16x16x32_bf16(a_h[im], b_h[in], acc[im][in], 0, 0, 0);
                acc[im][in] = __builtin_amdgcn_mfma_f32_16x16x32_bf16(a_h[im], b_l[in], acc[im][in], 0, 0, 0);
                acc[im][in] = __builtin_amdgcn_mfma_f32_16x16x32_bf16(a_l[im], b_h[in], acc[im][in], 0, 0, 0);
            }
    }
    const int qr = (lane >> 4) << 2;
#pragma unroll
    for (int im = 0; im < 2; ++im)
#pragma unroll
        for (int in = 0; in < 2; ++in) {
            int n = n0 + wn * 32 + in * 16 + fr;
            float bv = bias[n];
#pragma unroll
            for (int r = 0; r < 4; ++r) {
                int m = m0 + wm * 32 + im * 16 + qr + r;
                qkvb[(size_t)m * QKV_LD + n] = (u16)f2bf(acc[im][in][r] + bv);
            }
        }
}

// ------- V transpose: Vt[h][t][k] <- qkv[k][h*192+128+t] ------------------
__global__ __launch_bounds__(256) void transpose_v(const u16* __restrict__ qkvb,
                                                   u16* __restrict__ Vt)
{
    __shared__ u16 tile[64][72];
    const int h = blockIdx.y, k0 = blockIdx.x << 6;
    const int t = threadIdx.x;
    {
        int r = t >> 2, cg = (t & 3) << 4;
        const u16* src = qkvb + (size_t)(k0 + r) * QKV_LD + h * 192 + 128 + cg;
        *(uint4*)&tile[r][cg]     = *(const uint4*)src;
        *(uint4*)&tile[r][cg + 8] = *(const uint4*)(src + 8);
    }
    __syncthreads();
    {
        int c = t >> 2, kg = (t & 3) << 4;
        u16 tmp[16];
#pragma unroll
        for (int j = 0; j < 16; ++j) tmp[j] = tile[kg + j][c];
        u16* dst = Vt + ((size_t)h * 64 + c) * NT + k0 + kg;
        *(uint4*)dst       = *(uint4*)&tmp[0];
        *(uint4*)(dst + 8) = *(uint4*)&tmp[8];
    }
}

// ------- flash attention term 1: numpart[z] = exp(QK/8)@V, zpart = rowsums --
// grid (32 qb, 8 h, 4 z); per wave: 16 q-rows, k-strip 512, no inter-wave dep
__global__ __launch_bounds__(256) void flash_attn(const u16* __restrict__ qkvb,
    const u16* __restrict__ Vt, float* __restrict__ numpart,
    float* __restrict__ zpart)
{
    __shared__ u16 P[4][2][16][40];   // [wave][dbuf][q'][k'] bf16 exp tile
    const int h = blockIdx.y, z = blockIdx.z;
    const int w = threadIdx.x >> 6, lane = threadIdx.x & 63;
    const int fr = lane & 15, kd = (lane >> 4) << 3, qr = (lane >> 4) << 2;
    const int q0 = (blockIdx.x << 6) + (w << 4);
    const int kbase = z << 9;

    const u16* qb = qkvb + (size_t)(q0 + fr) * QKV_LD + h * 192 + kd;
    short8 qa0 = *(const short8*)(qb);
    short8 qa1 = *(const short8*)(qb + 32);
    const u16* kbp = qkvb + (size_t)kbase * QKV_LD + h * 192 + 64 + kd;
    const u16* vb  = Vt + ((size_t)h * 64 + fr) * NT + kbase + kd;

    v4f acc[4] = {};
    float zac[4] = {};
    int buf = 0;
    for (int kt = 0; kt < 512; kt += 32) {
#pragma unroll
        for (int ks = 0; ks < 2; ++ks) {
            const u16* kr = kbp + (size_t)(kt + ks * 16 + fr) * QKV_LD;
            short8 kb0 = *(const short8*)(kr);
            short8 kb1 = *(const short8*)(kr + 32);
            v4f c = {};
            c = __builtin_amdgcn_mfma_f32_16x16x32_bf16(qa0, kb0, c, 0, 0, 0);
            c = __builtin_amdgcn_mfma_f32_16x16x32_bf16(qa1, kb1, c, 0, 0, 0);
#pragma unroll
            for (int r = 0; r < 4; ++r) {
                float ex = __expf(c[r] * 0.125f);
                zac[r] += ex;
                P[w][buf][qr + r][ks * 16 + fr] = (u16)f2bf(ex);
            }
        }
        __syncthreads();   // cross-lane LDS visibility (write -> read)
        union { uint2 u2[2]; short8 s8; } pa;
        pa.u2[0] = *(uint2*)&P[w][buf][fr][kd];
        pa.u2[1] = *(uint2*)&P[w][buf][fr][kd + 4];
#pragma unroll
        for (int ti = 0; ti < 4; ++ti) {
            short8 bfr = *(const short8*)(vb + (size_t)(ti * 16) * NT + kt);
            acc[ti] = __builtin_amdgcn_mfma_f32_16x16x32_bf16(pa.s8, bfr, acc[ti], 0, 0, 0);
        }
        buf ^= 1;          // double buffer: next write doesn't clobber read buf
    }
    // z: reduce over the 16-lane col group (rows live in quads)
#pragma unroll
    for (int off = 1; off < 16; off <<= 1)
#pragma unroll
        for (int r = 0; r < 4; ++r) zac[r] += __shfl_xor(zac[r], off);
    if (fr == 0) {
#pragma unroll
        for (int r = 0; r < 4; ++r)
            zpart[((size_t)z * NH + h) * NT + q0 + qr + r] = zac[r];
    }
    float* np = numpart + (size_t)z * NT * EMBD;
#pragma unroll
    for (int ti = 0; ti < 4; ++ti)
#pragma unroll
        for (int r = 0; r < 4; ++r)
            np[(size_t)(q0 + qr + r) * EMBD + (h << 6) + (ti << 4) + fr] = acc[ti][r];
}

// ------- combine: y1 = (sum_z numpart) / (sum_z zpart) ----------------------
__global__ __launch_bounds__(256) void combine_num(const float* __restrict__ numpart,
    const float* __restrict__ zpart, float* __restrict__ y1)
{
    int i = (blockIdx.x * 256 + threadIdx.x) << 2;
    const int q = i >> 9, h = (i & 511) >> 6;
    float zs = 0.f;
#pragma unroll
    for (int z = 0; z < 4; ++z) zs += zpart[((size_t)z * NH + h) * NT + q];
    const float inv = 1.0f / zs;
    float4 a = *(const float4*)(numpart + i);
#pragma unroll
    for (int z = 1; z < 4; ++z) {
        float4 p = *(const float4*)(numpart + (size_t)z * NT * EMBD + i);
        a.x += p.x; a.y += p.y; a.z += p.z; a.w += p.w;
    }
    a.x *= inv; a.y *= inv; a.z *= inv; a.w *= inv;
    *(float4*)(y1 + i) = a;
}

// ---- bias term 2: y1 += (bias(angle) + bb) @ V  (triangle, frozen numerics)
__global__ __launch_bounds__(256) void bias_bv(const float* __restrict__ vec,
    const float* __restrict__ Wb, const float* __restrict__ bb,
    const u16* __restrict__ Vt, float* __restrict__ y1)
{
    __shared__ float flds[32];
    __shared__ float vql[96], vkl[96];
    __shared__ float bbl[8];
    __shared__ float ang_lds[1057];          // [qq*33 + kk]
    __shared__ float biasl[8 * 1057];        // [h*1057 + qq*33 + kk]

    const int t = threadIdx.x;
    int b = blockIdx.x, tq = 0, rem = 64;
    while (b >= rem) { b -= rem; ++tq; --rem; }
    const int tk = tq + b;
    const int q0 = tq << 5, k0 = tk << 5;

    if (t < 32) flds[t] = __fdiv_rn(__fdiv_rn((float)t, 31.0f), 0.1f);
    else if (t < 128) vql[t - 32] = vec[q0 * 3 + (t - 32)];
    else if (t < 224) vkl[t - 128] = vec[k0 * 3 + (t - 128)];
    else if (t < 232) bbl[t - 224] = bb[t - 224];
    __syncthreads();

    // phase 1a: angles for all 1024 pairs (frozen numerics)
    {
        const int qq = t & 31, kb = (t >> 5) << 2;
        const float a0 = vql[qq * 3], a1 = vql[qq * 3 + 1], a2 = vql[qq * 3 + 2];
#pragma unroll
        for (int j = 0; j < 4; ++j) {
            const int kk = kb + j;
            float c0 = vkl[kk * 3], c1 = vkl[kk * 3 + 1], c2 = vkl[kk * 3 + 2];
            float dot = __fadd_rn(__fadd_rn(__fmul_rn(a0, c0), __fmul_rn(a1, c1)),
                                  __fmul_rn(a2, c2));
            float dotc = fminf(fmaxf(dot, 0.0f), 1.0f);
            ang_lds[qq * 33 + kk] = __fdiv_rn(acosf(dotc), 0.001f);
        }
    }
    __syncthreads();

    // phase 1b: sincos features -> MFMA projection onto 8 heads
    {
        const int w = t >> 6, lane = t & 63;
        const int fr = lane & 15, kd = (lane >> 4) << 3, qr = (lane >> 4) << 2;
        short8 BS, BC;
#pragma unroll
        for (int j = 0; j < 8; ++j) {
            float ws = (fr < 8) ? Wb[(kd + j) * 8 + fr] : 0.0f;
            float wc = (fr < 8) ? Wb[(32 + kd + j) * 8 + fr] : 0.0f;
            BS[j] = (short)f2bf(ws);
            BC[j] = (short)f2bf(wc);
        }
        for (int tt = w; tt < 64; tt += 4) {
            int p = (tt << 4) + fr;
            float ang = ang_lds[(p >> 5) * 33 + (p & 31)];
            short8 AS, AC;
#pragma unroll
            for (int j = 0; j < 8; ++j) {
                float ph = __fmul_rn(flds[kd + j], ang);
                float rv = ph * 0.15915494309189535f;
                float rf = rv - floorf(rv);
                AS[j] = (short)f2bf(__builtin_amdgcn_sinf(rf));
                AC[j] = (short)f2bf(__builtin_amdgcn_cosf(rf));
            }
            v4f c = {};
            c = __builtin_amdgcn_mfma_f32_16x16x32_bf16(AS, BS, c, 0, 0, 0);
            c = __builtin_amdgcn_mfma_f32_16x16x32_bf16(AC, BC, c, 0, 0, 0);
            if (fr < 8) {
#pragma unroll
                for (int r = 0; r < 4; ++r) {
                    int pp = (tt << 4) + qr + r;
                    biasl[fr * 1057 + (pp >> 5) * 33 + (pp & 31)] = c[r];
                }
            }
        }
    }
    __syncthreads();

    // phase 2: y1 += (biasl + bb) @ V via MFMA + atomics, both orientations
    {
        const int w = t >> 6, lane = t & 63;
        const int fr = lane & 15, kd8 = (lane >> 4) << 3, qr = (lane >> 4) << 2;
        for (int u = w; u < 16; u += 4) {
            const int h = u >> 1, o = u & 1;
            if (o && tk == tq) continue;
            const float bv = bbl[h];
            short8 afr[2];
#pragma unroll
            for (int mi = 0; mi < 2; ++mi) {
                short8 a;
#pragma unroll
                for (int j = 0; j < 8; ++j) {
                    float val = (o == 0)
                        ? biasl[h * 1057 + (mi * 16 + fr) * 33 + kd8 + j] + bv
                        : biasl[h * 1057 + (kd8 + j) * 33 + mi * 16 + fr] + bv;
                    a[j] = (short)f2bf(val);
                }
                afr[mi] = a;
            }
            const int vrow0 = (o == 0) ? k0 : q0;   // V rows = contraction range
            const int orow0 = (o == 0) ? q0 : k0;   // output rows
            const u16* vb = Vt + ((size_t)h * 64) * NT + vrow0 + kd8;
#pragma unroll
            for (int ti = 0; ti < 4; ++ti) {
                short8 bfr = *(const short8*)(vb + (size_t)(ti * 16 + fr) * NT);
#pragma unroll
                for (int mi = 0; mi < 2; ++mi) {
                    v4f c = {};
                    c = __builtin_amdgcn_mfma_f32_16x16x32_bf16(afr[mi], bfr, c, 0, 0, 0);
#pragma unroll
                    for (int r = 0; r < 4; ++r)
                        atomicAdd(y1 + (size_t)(orow0 + mi * 16 + qr + r) * EMBD +
                                  (h << 6) + (ti << 4) + fr, c[r]);
                }
            }
        }
    }
}

// ------- y1 -> bf16 hi/lo ---------------------------------------------------
__global__ __launch_bounds__(256) void conv_y(const float* __restrict__ y1,
    u16* __restrict__ yh, u16* __restrict__ yl)
{
    int i = (blockIdx.x * 256 + threadIdx.x) << 2;
    float4 v = *(const float4*)(y1 + i);
    float f[4] = {v.x, v.y, v.z, v.w};
    unsigned int hi[4], lo[4];
#pragma unroll
    for (int j = 0; j < 4; ++j) {
        hi[j] = f2bf(f[j]);
        lo[j] = f2bf(f[j] - bf2f(hi[j]));
    }
    uint2 wh; wh.x = hi[0] | (hi[1] << 16); wh.y = hi[2] | (hi[3] << 16);
    uint2 wl; wl.x = lo[0] | (lo[1] << 16); wl.y = lo[2] | (lo[3] << 16);
    *(uint2*)(yh + i) = wh;
    *(uint2*)(yl + i) = wl;
}

// ------- out = y @ Wout + bout via split-precision bf16 MFMA ----------------
__global__ __launch_bounds__(256) void gemm_out_mfma(const u16* __restrict__ yh,
    const u16* __restrict__ yl, const u16* __restrict__ wh,
    const u16* __restrict__ wl, const float* __restrict__ bias,
    float* __restrict__ out)
{
    const int n0 = blockIdx.x << 6, m0 = blockIdx.y << 6;
    const int w = threadIdx.x >> 6, lane = threadIdx.x & 63;
    const int wm = w >> 1, wn = w & 1;
    const int fr = lane & 15, kd = (lane >> 4) << 3;

    const u16* ah0 = yh + (size_t)(m0 + wm * 32 + fr) * EMBD + kd;
    const u16* al0 = yl + (size_t)(m0 + wm * 32 + fr) * EMBD + kd;
    const u16* bh0 = wh + (size_t)(n0 + wn * 32 + fr) * EMBD + kd;
    const u16* bl0 = wl + (size_t)(n0 + wn * 32 + fr) * EMBD + kd;

    v4f acc[2][2] = {};
    for (int kc = 0; kc < EMBD; kc += 32) {
        short8 a_h[2], a_l[2], b_h[2], b_l[2];
#pragma unroll
        for (int im = 0; im < 2; ++im) {
            a_h[im] = *(const short8*)(ah0 + (size_t)im * 16 * EMBD + kc);
            a_l[im] = *(const short8*)(al0 + (size_t)im * 16 * EMBD + kc);
        }
#pragma unroll
        for (int in = 0; in < 2; ++in) {
            b_h[in] = *(const short8*)(bh0 + (size_t)in * 16 * EMBD + kc);
            b_l[in] = *(const short8*)(bl0 + (size_t)in * 16 * EMBD + kc);
        }
#pragma unroll
        for (int im = 0; im < 2; ++im)
#pragma unroll
            for (int in = 0; in < 2; ++in) {
                acc[im][in] = __builtin_amdgcn_mfma_f32_16x16x32_bf16(a_h[im], b_h[in], acc[im][in], 0, 0, 0);
                acc[im][in] = __builtin_amdgcn_mfma_f32_16x16x32_bf16(a_h[im], b_l[in], acc[im][in], 0, 0, 0);
                acc[im][in] = __builtin_amdgcn_mfma_f32_16x16x32_bf16(a_l[im], b_h[in], acc[im][in], 0, 0, 0);
            }
    }
    const int qr = (lane >> 4) << 2;
#pragma unroll
    for (int im = 0; im < 2; ++im)
#pragma unroll
        for (int in = 0; in < 2; ++in) {
            int n = n0 + wn * 32 + in * 16 + fr;
            float bv = bias[n];
#pragma unroll
            for (int r = 0; r < 4; ++r) {
                int m = m0 + wm * 32 + im * 16 + qr + r;
                out[(size_t)m * EMBD + n] = acc[im][in][r] + bv;
            }
        }
}

extern "C" void kernel_launch(void* const* d_in, const int* in_sizes, int n_in,
                              void* d_out, int out_size, void* d_ws, size_t ws_size,
                              hipStream_t stream)
{
    const float* x    = (const float*)d_in[0];
    const float* vec  = (const float*)d_in[1];
    const float* Wqkv = (const float*)d_in[2];
    const float* bqkv = (const float*)d_in[3];
    const float* Wb   = (const float*)d_in[4];
    const float* bb   = (const float*)d_in[5];
    const float* Wout = (const float*)d_in[6];
    const float* bout = (const float*)d_in[7];
    float* out = (float*)d_out;

    char* ws = (char*)d_ws;
    u16*   qkvb  = (u16*)(ws);                      //  6,291,456
    u16*   Vt    = (u16*)(ws + 6291456);            //  2,097,152
    float* zpart = (float*)(ws + 8388608);          //    262,144
    float* y1    = (float*)(ws + 8650752);          //  4,194,304
    u16*   yh    = (u16*)(ws + 12845056);           //  2,097,152
    u16*   yl    = (u16*)(ws + 14942208);           //  2,097,152
    float* nump  = (float*)(ws + 17039360);         // 16,777,216
    u16*   xh    = (u16*)(ws + 33816576);           //  2,097,152
    u16*   xl    = (u16*)(ws + 35913728);           //  2,097,152
    u16*   wth   = (u16*)(ws + 38010880);           //  1,572,864
    u16*   wtl   = (u16*)(ws + 39583744);           //  1,572,864
    u16*   woth  = (u16*)(ws + 41156608);           //    524,288
    u16*   wotl  = (u16*)(ws + 41680896);           //    524,288
    // total: 42,205,184 B

    split_x<<<1024, 256, 0, stream>>>(x, xh, xl);
    split_wt<<<dim3(24, 8), 256, 0, stream>>>(Wqkv, wth, wtl, QKV_LD);
    gemm_qkv_mfma<<<dim3(24, 32), 256, 0, stream>>>(xh, xl, wth, wtl, bqkv, qkvb);
    transpose_v<<<dim3(32, 8), 256, 0, stream>>>(qkvb, Vt);
    flash_attn<<<dim3(32, 8, 4), 256, 0, stream>>>(qkvb, Vt, nump, zpart);
    combine_num<<<1024, 256, 0, stream>>>(nump, zpart, y1);
    bias_bv<<<2080, 256, 0, stream>>>(vec, Wb, bb, Vt, y1);
    conv_y<<<1024, 256, 0, stream>>>(y1, yh, yl);
    split_wt<<<dim3(8, 8), 256, 0, stream>>>(Wout, woth, wotl, EMBD);
    gemm_out_mfma<<<dim3(8, 32), 256, 0, stream>>>(yh, yl, woth, wotl, bout, out);
}

// Round 9
// 283.777 us; speedup vs baseline: 1.4933x; 1.4933x over previous
//
#include <hip/hip_runtime.h>
#include <hip/hip_bf16.h>
#include <math.h>

#define NT 2048
#define EMBD 512
#define NH 8
#define QKV_LD 1536

typedef unsigned short u16;
typedef __attribute__((ext_vector_type(8))) short short8;
typedef __attribute__((ext_vector_type(4))) float v4f;

static __device__ __forceinline__ float bf2f(unsigned int u) {
    union { unsigned int i; float f; } c; c.i = u << 16; return c.f;
}
static __device__ __forceinline__ unsigned int f2bf(float x) {   // RNE
    union { float f; unsigned int u; } c; c.f = x;
    return (c.u + 0x7fffu + ((c.u >> 16) & 1u)) >> 16;
}

// ------- split x into bf16 hi/lo --------------------------------------------
__global__ __launch_bounds__(256) void split_x(const float* __restrict__ x,
    u16* __restrict__ xh, u16* __restrict__ xl)
{
    int i = (blockIdx.x * 256 + threadIdx.x) << 2;
    float4 v = *(const float4*)(x + i);
    float f[4] = {v.x, v.y, v.z, v.w};
    unsigned int hi[4], lo[4];
#pragma unroll
    for (int j = 0; j < 4; ++j) {
        hi[j] = f2bf(f[j]);
        lo[j] = f2bf(f[j] - bf2f(hi[j]));
    }
    uint2 wh; wh.x = hi[0] | (hi[1] << 16); wh.y = hi[2] | (hi[3] << 16);
    uint2 wl; wl.x = lo[0] | (lo[1] << 16); wl.y = lo[2] | (lo[3] << 16);
    *(uint2*)(xh + i) = wh;
    *(uint2*)(xl + i) = wl;
}

// ------- split+transpose W[K][N] -> Wt[n][k] bf16 hi/lo (row stride ld) -----
__global__ __launch_bounds__(256) void split_wt(const float* __restrict__ W,
    u16* __restrict__ wth, u16* __restrict__ wtl, int ld)
{
    __shared__ float tile[64][65];
    const int n0 = blockIdx.x << 6, k0 = blockIdx.y << 6;
    const int t = threadIdx.x;
    const int r = t >> 2, c4 = (t & 3) << 4;
#pragma unroll
    for (int j = 0; j < 4; ++j)
        *(float4*)&tile[r][c4 + (j << 2)] =
            *(const float4*)(W + (size_t)(k0 + r) * ld + n0 + c4 + (j << 2));
    __syncthreads();
    const int n_l = t >> 2;
    u16 th[16], tl[16];
#pragma unroll
    for (int j = 0; j < 16; ++j) {
        float f = tile[c4 + j][n_l];
        unsigned int h = f2bf(f);
        th[j] = (u16)h;
        tl[j] = (u16)f2bf(f - bf2f(h));
    }
    u16* dh = wth + (size_t)(n0 + n_l) * EMBD + k0 + c4;
    u16* dl = wtl + (size_t)(n0 + n_l) * EMBD + k0 + c4;
    *(uint4*)dh       = *(uint4*)&th[0];
    *(uint4*)(dh + 8) = *(uint4*)&th[8];
    *(uint4*)dl       = *(uint4*)&tl[0];
    *(uint4*)(dl + 8) = *(uint4*)&tl[8];
}

// ------- qkv = x @ Wqkv + b via split-precision bf16 MFMA -------------------
__global__ __launch_bounds__(256) void gemm_qkv_mfma(const u16* __restrict__ xh,
    const u16* __restrict__ xl, const u16* __restrict__ wth,
    const u16* __restrict__ wtl, const float* __restrict__ bias,
    u16* __restrict__ qkvb)
{
    const int n0 = blockIdx.x << 6, m0 = blockIdx.y << 6;
    const int w = threadIdx.x >> 6, lane = threadIdx.x & 63;
    const int wm = w >> 1, wn = w & 1;
    const int fr = lane & 15, kd = (lane >> 4) << 3;

    const u16* ah0 = xh + (size_t)(m0 + wm * 32 + fr) * EMBD + kd;
    const u16* al0 = xl + (size_t)(m0 + wm * 32 + fr) * EMBD + kd;
    const u16* bh0 = wth + (size_t)(n0 + wn * 32 + fr) * EMBD + kd;
    const u16* bl0 = wtl + (size_t)(n0 + wn * 32 + fr) * EMBD + kd;

    v4f acc[2][2] = {};
    for (int kc = 0; kc < EMBD; kc += 32) {
        short8 a_h[2], a_l[2], b_h[2], b_l[2];
#pragma unroll
        for (int im = 0; im < 2; ++im) {
            a_h[im] = *(const short8*)(ah0 + (size_t)im * 16 * EMBD + kc);
            a_l[im] = *(const short8*)(al0 + (size_t)im * 16 * EMBD + kc);
        }
#pragma unroll
        for (int in = 0; in < 2; ++in) {
            b_h[in] = *(const short8*)(bh0 + (size_t)in * 16 * EMBD + kc);
            b_l[in] = *(const short8*)(bl0 + (size_t)in * 16 * EMBD + kc);
        }
#pragma unroll
        for (int im = 0; im < 2; ++im)
#pragma unroll
            for (int in = 0; in < 2; ++in) {
                acc[im][in] = __builtin_amdgcn_mfma_f32_16x16x32_bf16(a_h[im], b_h[in], acc[im][in], 0, 0, 0);
                acc[im][in] = __builtin_amdgcn_mfma_f32_16x16x32_bf16(a_h[im], b_l[in], acc[im][in], 0, 0, 0);
                acc[im][in] = __builtin_amdgcn_mfma_f32_16x16x32_bf16(a_l[im], b_h[in], acc[im][in], 0, 0, 0);
            }
    }
    const int qr = (lane >> 4) << 2;
#pragma unroll
    for (int im = 0; im < 2; ++im)
#pragma unroll
        for (int in = 0; in < 2; ++in) {
            int n = n0 + wn * 32 + in * 16 + fr;
            float bv = bias[n];
#pragma unroll
            for (int r = 0; r < 4; ++r) {
                int m = m0 + wm * 32 + im * 16 + qr + r;
                qkvb[(size_t)m * QKV_LD + n] = (u16)f2bf(acc[im][in][r] + bv);
            }
        }
}

// ------- V transpose: Vt[h][t][k] <- qkv[k][h*192+128+t] ------------------
__global__ __launch_bounds__(256) void transpose_v(const u16* __restrict__ qkvb,
                                                   u16* __restrict__ Vt)
{
    __shared__ u16 tile[64][72];
    const int h = blockIdx.y, k0 = blockIdx.x << 6;
    const int t = threadIdx.x;
    {
        int r = t >> 2, cg = (t & 3) << 4;
        const u16* src = qkvb + (size_t)(k0 + r) * QKV_LD + h * 192 + 128 + cg;
        *(uint4*)&tile[r][cg]     = *(const uint4*)src;
        *(uint4*)&tile[r][cg + 8] = *(const uint4*)(src + 8);
    }
    __syncthreads();
    {
        int c = t >> 2, kg = (t & 3) << 4;
        u16 tmp[16];
#pragma unroll
        for (int j = 0; j < 16; ++j) tmp[j] = tile[kg + j][c];
        u16* dst = Vt + ((size_t)h * 64 + c) * NT + k0 + kg;
        *(uint4*)dst       = *(uint4*)&tmp[0];
        *(uint4*)(dst + 8) = *(uint4*)&tmp[8];
    }
}

// ------- flash term 1: nump[z] = exp(QK/8)@V (bf16), zpart = exp rowsums ----
// P is wave-private LDS: no __syncthreads needed (intra-wave lgkmcnt order)
__global__ __launch_bounds__(256) void flash_attn(const u16* __restrict__ qkvb,
    const u16* __restrict__ Vt, u16* __restrict__ nump,
    float* __restrict__ zpart)
{
    __shared__ u16 P[4][2][16][40];
    const int h = blockIdx.y, z = blockIdx.z;
    const int w = threadIdx.x >> 6, lane = threadIdx.x & 63;
    const int fr = lane & 15, kd = (lane >> 4) << 3, qr = (lane >> 4) << 2;
    const int q0 = (blockIdx.x << 6) + (w << 4);
    const int kbase = z << 9;

    const u16* qb = qkvb + (size_t)(q0 + fr) * QKV_LD + h * 192 + kd;
    short8 qa0 = *(const short8*)(qb);
    short8 qa1 = *(const short8*)(qb + 32);
    const u16* kbp = qkvb + (size_t)kbase * QKV_LD + h * 192 + 64 + kd;
    const u16* vb  = Vt + ((size_t)h * 64 + fr) * NT + kbase + kd;

    v4f acc[4] = {};
    float zac[4] = {};
    int buf = 0;
    for (int kt = 0; kt < 512; kt += 32) {
#pragma unroll
        for (int ks = 0; ks < 2; ++ks) {
            const u16* kr = kbp + (size_t)(kt + ks * 16 + fr) * QKV_LD;
            short8 kb0 = *(const short8*)(kr);
            short8 kb1 = *(const short8*)(kr + 32);
            v4f c = {};
            c = __builtin_amdgcn_mfma_f32_16x16x32_bf16(qa0, kb0, c, 0, 0, 0);
            c = __builtin_amdgcn_mfma_f32_16x16x32_bf16(qa1, kb1, c, 0, 0, 0);
#pragma unroll
            for (int r = 0; r < 4; ++r) {
                float ex = __expf(c[r] * 0.125f);
                zac[r] += ex;
                P[w][buf][qr + r][ks * 16 + fr] = (u16)f2bf(ex);
            }
        }
        union { uint2 u2[2]; short8 s8; } pa;
        pa.u2[0] = *(uint2*)&P[w][buf][fr][kd];
        pa.u2[1] = *(uint2*)&P[w][buf][fr][kd + 4];
#pragma unroll
        for (int ti = 0; ti < 4; ++ti) {
            short8 bfr = *(const short8*)(vb + (size_t)(ti * 16) * NT + kt);
            acc[ti] = __builtin_amdgcn_mfma_f32_16x16x32_bf16(pa.s8, bfr, acc[ti], 0, 0, 0);
        }
        buf ^= 1;
    }
#pragma unroll
    for (int off = 1; off < 16; off <<= 1)
#pragma unroll
        for (int r = 0; r < 4; ++r) zac[r] += __shfl_xor(zac[r], off);
    if (fr == 0) {
#pragma unroll
        for (int r = 0; r < 4; ++r)
            zpart[((size_t)z * NH + h) * NT + q0 + qr + r] = zac[r];
    }
    u16* np = nump + (size_t)z * NT * EMBD;
#pragma unroll
    for (int ti = 0; ti < 4; ++ti)
#pragma unroll
        for (int r = 0; r < 4; ++r)
            np[(size_t)(q0 + qr + r) * EMBD + (h << 6) + (ti << 4) + fr] =
                (u16)f2bf(acc[ti][r]);
}

// ---- bias matrix: bm[h][q][k] = bf16(bias(q,k)+bb[h]), triangle blocks -----
// Frozen numerics. Writes both orientations coalesced; no fetch, no atomics.
__global__ __launch_bounds__(256) void bias_mat(const float* __restrict__ vec,
    const float* __restrict__ Wb, const float* __restrict__ bb,
    u16* __restrict__ bm)
{
    __shared__ float flds[32];
    __shared__ float vql[96], vkl[96];
    __shared__ float bbl[8];
    __shared__ float ang_lds[1057];          // [qq*33 + kk]
    __shared__ float biasl[8 * 1057];        // [h*1057 + qq*33 + kk]

    const int t = threadIdx.x;
    int b = blockIdx.x, tq = 0, rem = 64;
    while (b >= rem) { b -= rem; ++tq; --rem; }
    const int tk = tq + b;
    const int q0 = tq << 5, k0 = tk << 5;

    if (t < 32) flds[t] = __fdiv_rn(__fdiv_rn((float)t, 31.0f), 0.1f);
    else if (t < 128) vql[t - 32] = vec[q0 * 3 + (t - 32)];
    else if (t < 224) vkl[t - 128] = vec[k0 * 3 + (t - 128)];
    else if (t < 232) bbl[t - 224] = bb[t - 224];
    __syncthreads();

    {   // phase 1a: angles (frozen numerics)
        const int qq = t & 31, kb = (t >> 5) << 2;
        const float a0 = vql[qq * 3], a1 = vql[qq * 3 + 1], a2 = vql[qq * 3 + 2];
#pragma unroll
        for (int j = 0; j < 4; ++j) {
            const int kk = kb + j;
            float c0 = vkl[kk * 3], c1 = vkl[kk * 3 + 1], c2 = vkl[kk * 3 + 2];
            float dot = __fadd_rn(__fadd_rn(__fmul_rn(a0, c0), __fmul_rn(a1, c1)),
                                  __fmul_rn(a2, c2));
            float dotc = fminf(fmaxf(dot, 0.0f), 1.0f);
            ang_lds[qq * 33 + kk] = __fdiv_rn(acosf(dotc), 0.001f);
        }
    }
    __syncthreads();

    {   // phase 1b: sincos features -> MFMA projection onto 8 heads
        const int w = t >> 6, lane = t & 63;
        const int fr = lane & 15, kd = (lane >> 4) << 3, qr = (lane >> 4) << 2;
        short8 BS, BC;
#pragma unroll
        for (int j = 0; j < 8; ++j) {
            float ws = (fr < 8) ? Wb[(kd + j) * 8 + fr] : 0.0f;
            float wc = (fr < 8) ? Wb[(32 + kd + j) * 8 + fr] : 0.0f;
            BS[j] = (short)f2bf(ws);
            BC[j] = (short)f2bf(wc);
        }
        for (int tt = w; tt < 64; tt += 4) {
            int p = (tt << 4) + fr;
            float ang = ang_lds[(p >> 5) * 33 + (p & 31)];
            short8 AS, AC;
#pragma unroll
            for (int j = 0; j < 8; ++j) {
                float ph = __fmul_rn(flds[kd + j], ang);
                float rv = ph * 0.15915494309189535f;
                float rf = rv - floorf(rv);
                AS[j] = (short)f2bf(__builtin_amdgcn_sinf(rf));
                AC[j] = (short)f2bf(__builtin_amdgcn_cosf(rf));
            }
            v4f c = {};
            c = __builtin_amdgcn_mfma_f32_16x16x32_bf16(AS, BS, c, 0, 0, 0);
            c = __builtin_amdgcn_mfma_f32_16x16x32_bf16(AC, BC, c, 0, 0, 0);
            if (fr < 8) {
#pragma unroll
                for (int r = 0; r < 4; ++r) {
                    int pp = (tt << 4) + qr + r;
                    biasl[fr * 1057 + (pp >> 5) * 33 + (pp & 31)] = c[r];
                }
            }
        }
    }
    __syncthreads();

    // phase 2: store both orientations, coalesced uint2 writes
    const int row = t >> 3, c4 = (t & 7) << 2;
#pragma unroll
    for (int h = 0; h < 8; ++h) {
        const float bv = bbl[h];
        unsigned int o[4];
#pragma unroll
        for (int j = 0; j < 4; ++j)
            o[j] = f2bf(biasl[h * 1057 + row * 33 + c4 + j] + bv);
        uint2 wv; wv.x = o[0] | (o[1] << 16); wv.y = o[2] | (o[3] << 16);
        *(uint2*)(bm + ((size_t)h * NT + q0 + row) * NT + k0 + c4) = wv;
    }
    if (tk != tq) {
#pragma unroll
        for (int h = 0; h < 8; ++h) {
            const float bv = bbl[h];
            unsigned int o[4];
#pragma unroll
            for (int j = 0; j < 4; ++j)
                o[j] = f2bf(biasl[h * 1057 + (c4 + j) * 33 + row] + bv);
            uint2 wv; wv.x = o[0] | (o[1] << 16); wv.y = o[2] | (o[3] << 16);
            *(uint2*)(bm + ((size_t)h * NT + k0 + row) * NT + q0 + c4) = wv;
        }
    }
}

// ------- bpart[z] = bm @ V via bf16 MFMA (split-K=2), frags from global -----
__global__ __launch_bounds__(256) void biasv_mfma(const u16* __restrict__ bm,
    const u16* __restrict__ Vt, float* __restrict__ bpart)
{
    const int h = blockIdx.y, z = blockIdx.z;
    const int q0 = (blockIdx.x << 6) + ((threadIdx.x >> 6) << 4);
    const int lane = threadIdx.x & 63;
    const int fr = lane & 15;
    const int kd = (lane >> 4) << 3;
    const int kbase = z << 10;

    const u16* arow  = bm + (size_t)(h * NT + q0 + fr) * NT + kbase + kd;
    const u16* vbase = Vt + ((size_t)h * 64 + fr) * NT + kbase + kd;

    v4f c[4] = {};
    for (int ks = 0; ks < 1024; ks += 32) {
        short8 a = *(const short8*)(arow + ks);
#pragma unroll
        for (int nt = 0; nt < 4; ++nt) {
            short8 bv = *(const short8*)(vbase + (size_t)nt * 16 * NT + ks);
            c[nt] = __builtin_amdgcn_mfma_f32_16x16x32_bf16(a, bv, c[nt], 0, 0, 0);
        }
    }
    float* bp = bpart + (size_t)z * NT * EMBD;
    const int qr = (lane >> 4) << 2;
#pragma unroll
    for (int nt = 0; nt < 4; ++nt)
#pragma unroll
        for (int r = 0; r < 4; ++r)
            bp[(size_t)(q0 + qr + r) * EMBD + (h << 6) + (nt << 4) + fr] = c[nt][r];
}

// ------- combine: y = (sum_z nump)/(sum_z zpart) + sum_z bpart -> yh/yl -----
__global__ __launch_bounds__(256) void combine_emit(const u16* __restrict__ nump,
    const float* __restrict__ zpart, const float* __restrict__ bpart,
    u16* __restrict__ yh, u16* __restrict__ yl)
{
    const int MN = NT * EMBD;
    int i = (blockIdx.x * 256 + threadIdx.x) << 2;
    const int q = i >> 9, h = (i & 511) >> 6;
    float zs = 0.f;
#pragma unroll
    for (int z = 0; z < 4; ++z) zs += zpart[((size_t)z * NH + h) * NT + q];
    const float inv = 1.0f / zs;
    float a[4] = {};
#pragma unroll
    for (int z = 0; z < 4; ++z) {
        uint2 r = *(const uint2*)(nump + (size_t)z * MN + i);
        a[0] += bf2f(r.x & 0xffffu); a[1] += bf2f(r.x >> 16);
        a[2] += bf2f(r.y & 0xffffu); a[3] += bf2f(r.y >> 16);
    }
    float bsum[4] = {};
#pragma unroll
    for (int z = 0; z < 2; ++z) {
        float4 p = *(const float4*)(bpart + (size_t)z * MN + i);
        bsum[0] += p.x; bsum[1] += p.y; bsum[2] += p.z; bsum[3] += p.w;
    }
    unsigned int hi[4], lo[4];
#pragma unroll
    for (int j = 0; j < 4; ++j) {
        float y = a[j] * inv + bsum[j];
        hi[j] = f2bf(y);
        lo[j] = f2bf(y - bf2f(hi[j]));
    }
    uint2 wh; wh.x = hi[0] | (hi[1] << 16); wh.y = hi[2] | (hi[3] << 16);
    uint2 wl; wl.x = lo[0] | (lo[1] << 16); wl.y = lo[2] | (lo[3] << 16);
    *(uint2*)(yh + i) = wh;
    *(uint2*)(yl + i) = wl;
}

// ------- out = y @ Wout + bout via split-precision bf16 MFMA ----------------
__global__ __launch_bounds__(256) void gemm_out_mfma(const u16* __restrict__ yh,
    const u16* __restrict__ yl, const u16* __restrict__ wh,
    const u16* __restrict__ wl, const float* __restrict__ bias,
    float* __restrict__ out)
{
    const int n0 = blockIdx.x << 6, m0 = blockIdx.y << 6;
    const int w = threadIdx.x >> 6, lane = threadIdx.x & 63;
    const int wm = w >> 1, wn = w & 1;
    const int fr = lane & 15, kd = (lane >> 4) << 3;

    const u16* ah0 = yh + (size_t)(m0 + wm * 32 + fr) * EMBD + kd;
    const u16* al0 = yl + (size_t)(m0 + wm * 32 + fr) * EMBD + kd;
    const u16* bh0 = wh + (size_t)(n0 + wn * 32 + fr) * EMBD + kd;
    const u16* bl0 = wl + (size_t)(n0 + wn * 32 + fr) * EMBD + kd;

    v4f acc[2][2] = {};
    for (int kc = 0; kc < EMBD; kc += 32) {
        short8 a_h[2], a_l[2], b_h[2], b_l[2];
#pragma unroll
        for (int im = 0; im < 2; ++im) {
            a_h[im] = *(const short8*)(ah0 + (size_t)im * 16 * EMBD + kc);
            a_l[im] = *(const short8*)(al0 + (size_t)im * 16 * EMBD + kc);
        }
#pragma unroll
        for (int in = 0; in < 2; ++in) {
            b_h[in] = *(const short8*)(bh0 + (size_t)in * 16 * EMBD + kc);
            b_l[in] = *(const short8*)(bl0 + (size_t)in * 16 * EMBD + kc);
        }
#pragma unroll
        for (int im = 0; im < 2; ++im)
#pragma unroll
            for (int in = 0; in < 2; ++in) {
                acc[im][in] = __builtin_amdgcn_mfma_f32_16x16x32_bf16(a_h[im], b_h[in], acc[im][in], 0, 0, 0);
                acc[im][in] = __builtin_amdgcn_mfma_f32_16x16x32_bf16(a_h[im], b_l[in], acc[im][in], 0, 0, 0);
                acc[im][in] = __builtin_amdgcn_mfma_f32_16x16x32_bf16(a_l[im], b_h[in], acc[im][in], 0, 0, 0);
            }
    }
    const int qr = (lane >> 4) << 2;
#pragma unroll
    for (int im = 0; im < 2; ++im)
#pragma unroll
        for (int in = 0; in < 2; ++in) {
            int n = n0 + wn * 32 + in * 16 + fr;
            float bv = bias[n];
#pragma unroll
            for (int r = 0; r < 4; ++r) {
                int m = m0 + wm * 32 + im * 16 + qr + r;
                out[(size_t)m * EMBD + n] = acc[im][in][r] + bv;
            }
        }
}

extern "C" void kernel_launch(void* const* d_in, const int* in_sizes, int n_in,
                              void* d_out, int out_size, void* d_ws, size_t ws_size,
                              hipStream_t stream)
{
    const float* x    = (const float*)d_in[0];
    const float* vec  = (const float*)d_in[1];
    const float* Wqkv = (const float*)d_in[2];
    const float* bqkv = (const float*)d_in[3];
    const float* Wb   = (const float*)d_in[4];
    const float* bb   = (const float*)d_in[5];
    const float* Wout = (const float*)d_in[6];
    const float* bout = (const float*)d_in[7];
    float* out = (float*)d_out;

    char* ws = (char*)d_ws;
    u16*   qkvb  = (u16*)(ws);                      //  6,291,456
    u16*   Vt    = (u16*)(ws + 6291456);            //  2,097,152
    float* zpart = (float*)(ws + 8388608);          //    262,144
    u16*   nump  = (u16*)(ws + 8650752);            //  8,388,608 (4 x bf16)
    float* bpart = (float*)(ws + 17039360);         //  8,388,608 (2 x f32)
    u16*   yh    = (u16*)(ws + 25427968);           //  2,097,152
    u16*   yl    = (u16*)(ws + 27525120);           //  2,097,152
    u16*   bm    = (u16*)(ws + 29622272);           // 67,108,864
    // transients alias bm (bm written by bias_mat AFTER gemm_qkv consumed them)
    u16*   xh    = (u16*)(ws + 29622272);
    u16*   xl    = (u16*)(ws + 31719424);
    u16*   wth   = (u16*)(ws + 33816576);
    u16*   wtl   = (u16*)(ws + 35389440);
    // Wout split aliases bpart tail? No: placed after bm is consumed by biasv.
    u16*   woth  = (u16*)(ws + 29622272);           // written after biasv_mfma
    u16*   wotl  = (u16*)(ws + 30146560);
    // total: 96,731,136 B (< proven-working 100.8 MB)

    split_x<<<1024, 256, 0, stream>>>(x, xh, xl);
    split_wt<<<dim3(24, 8), 256, 0, stream>>>(Wqkv, wth, wtl, QKV_LD);
    gemm_qkv_mfma<<<dim3(24, 32), 256, 0, stream>>>(xh, xl, wth, wtl, bqkv, qkvb);
    transpose_v<<<dim3(32, 8), 256, 0, stream>>>(qkvb, Vt);
    flash_attn<<<dim3(32, 8, 4), 256, 0, stream>>>(qkvb, Vt, nump, zpart);
    bias_mat<<<2080, 256, 0, stream>>>(vec, Wb, bb, bm);
    biasv_mfma<<<dim3(32, 8, 2), 256, 0, stream>>>(bm, Vt, bpart);
    combine_emit<<<1024, 256, 0, stream>>>(nump, zpart, bpart, yh, yl);
    split_wt<<<dim3(8, 8), 256, 0, stream>>>(Wout, woth, wotl, EMBD);
    gemm_out_mfma<<<dim3(8, 32), 256, 0, stream>>>(yh, yl, woth, wotl, bout, out);
}